// Round 6
// baseline (317.968 us; speedup 1.0000x reference)
//
#include <hip/hip_runtime.h>

typedef unsigned int u32;
typedef unsigned short u16;
typedef __attribute__((ext_vector_type(8))) short bf16x8;
typedef __attribute__((ext_vector_type(4))) float f32x4;

constexpr int BATCH = 32;
constexpr int DIM   = 256;
constexpr int NPTS  = 512;
constexpr int NH    = 8;
constexpr int KD    = 16;
constexpr int DHEAD = 64;
constexpr int NH_KD = 128;
constexpr int DH    = 512;

__device__ __forceinline__ float bflo(u32 u){ return __uint_as_float(u << 16); }
__device__ __forceinline__ float bfhi(u32 u){ return __uint_as_float(u & 0xffff0000u); }
__device__ __forceinline__ float bf2f(u16 u){ return __uint_as_float(((u32)u) << 16); }
__device__ __forceinline__ u32 f2bf_bits(float f){
  u32 u = __float_as_uint(f);
  return (u + 0x7fffu + ((u >> 16) & 1u)) >> 16;
}
__device__ __forceinline__ u32 pack2bf(float a, float b){
  return f2bf_bits(a) | (f2bf_bits(b) << 16);
}

union B8 { bf16x8 v; uint2 u2[2]; };

// ---------------------------------------------------------------------------
// K0: fold scale into weights, convert to bf16.
// ---------------------------------------------------------------------------
__global__ __launch_bounds__(256) void k_prep(
    const float* __restrict__ wq, const float* __restrict__ sq,
    const float* __restrict__ wp, const float* __restrict__ sp,
    u32* __restrict__ wqb, u32* __restrict__ pwb)
{
  int t = blockIdx.x * 256 + threadIdx.x;
  if (t < 98304){                      // 768*256/2
    int i = 2*t;
    float s = sq[i >> 8];
    wqb[t] = pack2bf(wq[i]*s, wq[i+1]*s);
  } else {
    int j = t - 98304;                 // 256*512/2
    int i = 2*j;
    float s = sp[i >> 9];
    pwb[j] = pack2bf(wp[i]*s, wp[i+1]*s);
  }
}

// ---------------------------------------------------------------------------
// K1: qkv MFMA GEMM (unchanged from R5). C[o 768][n 512] per batch, K=256.
// ---------------------------------------------------------------------------
__global__ __launch_bounds__(256) void k_qkv(
    const float* __restrict__ x, const u16* __restrict__ wqb,
    const float* __restrict__ bias,
    u16* __restrict__ qfb, u16* __restrict__ kb, u16* __restrict__ vb)
{
  __shared__ __align__(16) u16 Xl[128*36];

  const int Mblk = blockIdx.x, Nblk = blockIdx.y, b = blockIdx.z;
  const int tid = threadIdx.x, wave = tid >> 6, lane = tid & 63;
  const int wm = wave >> 1, wn = wave & 1;
  const int c = lane & 15, q = lane >> 4;
  const int Mbase = Mblk*128 + wm*64;

  f32x4 acc[4][4];
  #pragma unroll
  for (int mt = 0; mt < 4; mt++){
    f32x4 bi;
    #pragma unroll
    for (int r = 0; r < 4; r++) bi[r] = bias[Mbase + mt*16 + q*4 + r];
    #pragma unroll
    for (int nt = 0; nt < 4; nt++) acc[mt][nt] = bi;
  }

  const float* xb = x + (size_t)b*DIM*NPTS + Nblk*128;

  for (int kc8 = 0; kc8 < 8; kc8++){
    const int kc = kc8*32;
    __syncthreads();
    #pragma unroll
    for (int it = 0; it < 4; it++){
      int n2 = 2*((tid & 31) + 32*(it & 1));
      int cc = 2*((tid >> 5) + 8*(it >> 1));
      const float* xr = xb + (size_t)(kc + cc)*NPTS + n2;
      float2 A = *(const float2*)xr;
      float2 Bv = *(const float2*)(xr + NPTS);
      *(u32*)(Xl + (size_t)n2*36 + cc)     = pack2bf(A.x, Bv.x);
      *(u32*)(Xl + (size_t)(n2+1)*36 + cc) = pack2bf(A.y, Bv.y);
    }
    __syncthreads();

    bf16x8 aW[4];
    #pragma unroll
    for (int mt = 0; mt < 4; mt++)
      aW[mt] = *(const bf16x8*)(wqb + (size_t)(Mbase + mt*16 + c)*256 + kc + q*8);
    B8 bX[4];
    #pragma unroll
    for (int nt = 0; nt < 4; nt++){
      const u16* base = Xl + (size_t)(wn*64 + nt*16 + c)*36 + q*8;
      bX[nt].u2[0] = *(const uint2*)(base);
      bX[nt].u2[1] = *(const uint2*)(base + 4);
    }
    #pragma unroll
    for (int mt = 0; mt < 4; mt++)
      #pragma unroll
      for (int nt = 0; nt < 4; nt++)
        acc[mt][nt] = __builtin_amdgcn_mfma_f32_16x16x32_bf16(
            aW[mt], bX[nt].v, acc[mt][nt], 0, 0, 0);
  }

  #pragma unroll
  for (int mt = 0; mt < 4; mt++){
    const int ob = wm*64 + mt*16 + q*4;
    #pragma unroll
    for (int nt = 0; nt < 4; nt++){
      const int n = Nblk*128 + wn*64 + nt*16 + c;
      #pragma unroll
      for (int r = 0; r < 4; r++){
        u16 bv = (u16)f2bf_bits(acc[mt][nt][r]);
        int ol = ob + r;
        if (Mblk == 0){
          qfb[((size_t)b*NH_KD + ol)*NPTS + n] = bv;
        } else if (Mblk == 1){
          kb[(((size_t)b*NH + (ol >> 4))*NPTS + n)*16 + (ol & 15)] = bv;
        } else {
          int d = (Mblk - 2)*128 + ol;
          vb[((size_t)b*DH + d)*NPTS + n] = bv;
        }
      }
    }
  }
}

// ---------------------------------------------------------------------------
// K2: depthwise 3x3x3 conv + scale/bias, x0.25 folded, bf16 in/out.
// ---------------------------------------------------------------------------
__global__ __launch_bounds__(512) void k_dw(
    const u16* __restrict__ qfb, const float* __restrict__ dww,
    const float* __restrict__ dws, const float* __restrict__ dwb,
    u16* __restrict__ qb)
{
  const int bc = blockIdx.x;            // b*128 + ch
  const int b  = bc >> 7;
  const int ch = bc & 127;
  const int n  = threadIdx.x;
  const int z = n >> 6, y = (n >> 3) & 7, xx = n & 7;
  float wv[27];
  #pragma unroll
  for (int i = 0; i < 27; i++) wv[i] = dww[ch*27 + i];
  const u16* qp = qfb + (size_t)bc * NPTS;
  float acc = 0.f;
  #pragma unroll
  for (int dz = 0; dz < 3; dz++){
    int zz = z + dz - 1; if ((unsigned)zz > 7u) continue;
    #pragma unroll
    for (int dy = 0; dy < 3; dy++){
      int yy = y + dy - 1; if ((unsigned)yy > 7u) continue;
      #pragma unroll
      for (int dx = 0; dx < 3; dx++){
        int xw = xx + dx - 1; if ((unsigned)xw > 7u) continue;
        acc += bf2f(qp[zz*64 + yy*8 + xw]) * wv[dz*9 + dy*3 + dx];
      }
    }
  }
  acc = (acc * dws[ch] + dwb[ch]) * 0.25f;   // fold 1/sqrt(KD)
  int hh = ch >> 4, cc = ch & 15;
  qb[(((size_t)b*NH + hh)*NPTS + n)*16 + cc] = (u16)f2bf_bits(acc);
}

// ---------------------------------------------------------------------------
// K_bias: bf16 bias table in MFMA C-layout order:
// biasb[h][nt 32][mt 32][lane 64][r 4] u16; lane reads uint2 in k_attn.
// ---------------------------------------------------------------------------
__global__ __launch_bounds__(256) void k_bias(
    const float* __restrict__ ab, const int* __restrict__ bidx,
    u32* __restrict__ biasb)
{
  const int blk = blockIdx.x;
  const int nt = blk >> 5, mt = blk & 31;
  const int lane = threadIdx.x & 63;
  const int h0 = threadIdx.x >> 6;
  const int cq = lane >> 4;
  const int m = mt*16 + (lane & 15);
  int idx[4];
  #pragma unroll
  for (int r = 0; r < 4; r++)
    idx[r] = bidx[(size_t)(nt*16 + cq*4 + r)*NPTS + m];
  for (int h = h0; h < NH; h += 4){
    float v0 = ab[h*NPTS + idx[0]], v1 = ab[h*NPTS + idx[1]];
    float v2 = ab[h*NPTS + idx[2]], v3 = ab[h*NPTS + idx[3]];
    u32* dst = biasb + (((size_t)(h*32 + nt)*32 + mt)*64 + lane)*2;
    dst[0] = pack2bf(v0, v1);
    dst[1] = pack2bf(v2, v3);
  }
}

// ---------------------------------------------------------------------------
// K3: barrier-free MFMA flash attention. Block = (64-row tile, h, b), 4 waves,
// each wave one 16-row n-tile, fully independent (no __syncthreads).
// K/V/bias B-frags straight from global (L2-hot); only P goes through
// wave-private swizzled LDS (stride 144 u16, XOR swizzle keyed on row).
// Fixed-shift softmax: p = exp(s) unnormalized, O /= l at the end.
// LDS: 4 waves x 16 x 144 u16 = 18,432 B -> 4 blocks/CU at launch_bounds(256,4).
// ---------------------------------------------------------------------------
__global__ __launch_bounds__(256, 4) void k_attn(
    const u16* __restrict__ qb, const u16* __restrict__ kb,
    const u16* __restrict__ vb, const u16* __restrict__ biasb,
    u32* __restrict__ attnout)
{
  __shared__ __align__(16) u16 Plds[4*16*144];

  const int tg = blockIdx.x, h = blockIdx.y, b = blockIdx.z;
  const int tid = threadIdx.x, wave = tid >> 6, lane = tid & 63;
  const int c = lane & 15, q = lane >> 4;
  const int bh = b*NH + h;
  const int n0 = tg*64 + wave*16;

  const bf16x8 zfrag = {0,0,0,0,0,0,0,0};
  bf16x8 aQ = zfrag;
  if (q < 2)
    aQ = *(const bf16x8*)(qb + (((size_t)bh*NPTS + n0 + c) << 4) + q*8);

  const u16* kbh = kb + ((size_t)bh*NPTS) * 16;
  const u16* vbh = vb + ((size_t)b*DH + h*DHEAD) * NPTS;
  const u16* biasw = biasb + (((size_t)(h*32) + (tg*4 + wave)) * 32) * 256 + lane*4;

  f32x4 O0={0,0,0,0}, O1={0,0,0,0}, O2={0,0,0,0}, O3={0,0,0,0};
  f32x4 l_run = {0,0,0,0};
  u16* Pw = Plds + wave*16*144;
  const int rswz = ((c&3)<<3) | ((c>>2)<<5);    // read swizzle key for row c

  #pragma unroll
  for (int chunk = 0; chunk < 4; chunk++){
    const int mca = chunk*128;
    // ---- scores: 8 m-tiles, C initialized with bf16 bias ----
    f32x4 S[8];
    #pragma unroll
    for (int mt = 0; mt < 8; mt++){
      bf16x8 bK = zfrag;
      if (q < 2)
        bK = *(const bf16x8*)(kbh + (((size_t)(mca + mt*16 + c)) << 4) + q*8);
      uint2 bu = *(const uint2*)(biasw + (size_t)(chunk*8 + mt)*256);
      f32x4 bias4;
      bias4[0] = bflo(bu.x); bias4[1] = bfhi(bu.x);
      bias4[2] = bflo(bu.y); bias4[3] = bfhi(bu.y);
      S[mt] = __builtin_amdgcn_mfma_f32_16x16x32_bf16(aQ, bK, bias4, 0, 0, 0);
    }
    // ---- fixed-shift softmax: store unnormalized exp, accumulate l ----
    #pragma unroll
    for (int mt = 0; mt < 8; mt++){
      #pragma unroll
      for (int r = 0; r < 4; r++){
        float e = __expf(S[mt][r]);
        l_run[r] += e;
        int colw = (mt*16 + c) ^ (r<<3) ^ (q<<5);
        Pw[(q*4 + r)*144 + colw] = (u16)f2bf_bits(e);
      }
    }
    // ---- PV: 4 K-steps of 32 m, 4 d-tiles, V frags from global ----
    #pragma unroll
    for (int ks = 0; ks < 4; ks++){
      bf16x8 aP = *(const bf16x8*)(Pw + c*144 + ((ks*32 + q*8) ^ rswz));
      const int mv = mca + ks*32 + q*8;
      bf16x8 b0 = *(const bf16x8*)(vbh + (size_t)( 0 + c)*NPTS + mv);
      bf16x8 b1 = *(const bf16x8*)(vbh + (size_t)(16 + c)*NPTS + mv);
      bf16x8 b2 = *(const bf16x8*)(vbh + (size_t)(32 + c)*NPTS + mv);
      bf16x8 b3 = *(const bf16x8*)(vbh + (size_t)(48 + c)*NPTS + mv);
      O0 = __builtin_amdgcn_mfma_f32_16x16x32_bf16(aP, b0, O0, 0, 0, 0);
      O1 = __builtin_amdgcn_mfma_f32_16x16x32_bf16(aP, b1, O1, 0, 0, 0);
      O2 = __builtin_amdgcn_mfma_f32_16x16x32_bf16(aP, b2, O2, 0, 0, 0);
      O3 = __builtin_amdgcn_mfma_f32_16x16x32_bf16(aP, b3, O3, 0, 0, 0);
    }
  }

  // ---- l reduction across the 16 column-lanes of each row ----
  #pragma unroll
  for (int off = 1; off < 16; off <<= 1)
    #pragma unroll
    for (int r = 0; r < 4; r++) l_run[r] += __shfl_xor(l_run[r], off, 64);

  // ---- epilogue: 1/l, relu, transpose via wave-private LDS, bf16 store ----
  float* outl = (float*)Pw;   // 16 x 65 fp32 = 4160 B <= 4608 B region
  f32x4 inv;
  #pragma unroll
  for (int r = 0; r < 4; r++) inv[r] = 1.0f / l_run[r];
  #pragma unroll
  for (int r = 0; r < 4; r++){
    outl[(q*4+r)*65 +  0 + c] = fmaxf(O0[r]*inv[r], 0.f);
    outl[(q*4+r)*65 + 16 + c] = fmaxf(O1[r]*inv[r], 0.f);
    outl[(q*4+r)*65 + 32 + c] = fmaxf(O2[r]*inv[r], 0.f);
    outl[(q*4+r)*65 + 48 + c] = fmaxf(O3[r]*inv[r], 0.f);
  }
  {
    const int nl = lane >> 2, seg = lane & 3;
    u32 buf[8];
    #pragma unroll
    for (int j = 0; j < 8; j++)
      buf[j] = pack2bf(outl[nl*65 + seg*16 + 2*j], outl[nl*65 + seg*16 + 2*j + 1]);
    u32* dst = attnout + ((size_t)(b*NPTS + n0 + nl))*(DH/2) + h*32 + seg*8;
    *(uint4*)dst       = make_uint4(buf[0], buf[1], buf[2], buf[3]);
    *(uint4*)(dst + 4) = make_uint4(buf[4], buf[5], buf[6], buf[7]);
  }
}

// ---------------------------------------------------------------------------
// K4: proj MFMA GEMM (unchanged from R5).
// ---------------------------------------------------------------------------
__global__ __launch_bounds__(256) void k_proj(
    const u16* __restrict__ attn, const u16* __restrict__ pwb,
    const float* __restrict__ bias, float* __restrict__ out)
{
  const int Mblk = blockIdx.x, Nblk = blockIdx.y, b = blockIdx.z;
  const int tid = threadIdx.x, wave = tid >> 6, lane = tid & 63;
  const int wm = wave >> 1, wn = wave & 1;
  const int c = lane & 15, q = lane >> 4;
  const int Mbase = Mblk*128 + wm*64;
  const int Nbase = Nblk*128 + wn*64;

  f32x4 acc[4][4];
  #pragma unroll
  for (int mt = 0; mt < 4; mt++){
    f32x4 bi;
    #pragma unroll
    for (int r = 0; r < 4; r++) bi[r] = bias[Mbase + mt*16 + q*4 + r];
    #pragma unroll
    for (int nt = 0; nt < 4; nt++) acc[mt][nt] = bi;
  }

  const u16* arow = attn + (size_t)b*NPTS*DH;

  for (int kc8 = 0; kc8 < 16; kc8++){
    const int kc = kc8*32;
    bf16x8 aW[4], bA[4];
    #pragma unroll
    for (int mt = 0; mt < 4; mt++)
      aW[mt] = *(const bf16x8*)(pwb + (size_t)(Mbase + mt*16 + c)*DH + kc + q*8);
    #pragma unroll
    for (int nt = 0; nt < 4; nt++)
      bA[nt] = *(const bf16x8*)(arow + (size_t)(Nbase + nt*16 + c)*DH + kc + q*8);
    #pragma unroll
    for (int mt = 0; mt < 4; mt++)
      #pragma unroll
      for (int nt = 0; nt < 4; nt++)
        acc[mt][nt] = __builtin_amdgcn_mfma_f32_16x16x32_bf16(
            aW[mt], bA[nt], acc[mt][nt], 0, 0, 0);
  }

  #pragma unroll
  for (int mt = 0; mt < 4; mt++){
    #pragma unroll
    for (int nt = 0; nt < 4; nt++){
      const int n = Nbase + nt*16 + c;
      #pragma unroll
      for (int r = 0; r < 4; r++){
        int o = Mbase + mt*16 + q*4 + r;
        out[((size_t)b*DIM + o)*NPTS + n] = acc[mt][nt][r];
      }
    }
  }
}

// ---------------------------------------------------------------------------
extern "C" void kernel_launch(void* const* d_in, const int* in_sizes, int n_in,
                              void* d_out, int out_size, void* d_ws, size_t ws_size,
                              hipStream_t stream)
{
  const float* x     = (const float*)d_in[0];
  const float* qkv_w = (const float*)d_in[1];
  const float* qkv_s = (const float*)d_in[2];
  const float* qkv_b = (const float*)d_in[3];
  const float* dw_w  = (const float*)d_in[4];
  const float* dw_s  = (const float*)d_in[5];
  const float* dw_b  = (const float*)d_in[6];
  const float* ab    = (const float*)d_in[7];
  const float* pw    = (const float*)d_in[8];
  const float* ps    = (const float*)d_in[9];
  const float* pb    = (const float*)d_in[10];
  const int* bidx    = (const int*)d_in[11];

  char* ws = (char*)d_ws;
  u16*   qfb   = (u16*)  (ws);                  //  4 MB (B,128,512) bf16
  u16*   qb    = (u16*)  (ws + ( 4u << 20));    //  4 MB (B,8,512,16) bf16
  u16*   kb    = (u16*)  (ws + ( 8u << 20));    //  4 MB (B,8,512,16) bf16
  u16*   vb    = (u16*)  (ws + (12u << 20));    // 16 MB (B,512,512) bf16 [b][d][m]
  u32*   attn  = (u32*)  (ws + (28u << 20));    // 16 MB (B,512,512) bf16 rows [n][dh]
  u32*   biasb = (u32*)  (ws + (44u << 20));    //  4 MB (8,32,32,64,4) bf16 C-layout
  u32*   wqb   = (u32*)  (ws + (48u << 20));    // 384 KB (768,256) bf16
  u32*   pwb   = (u32*)  (ws + (49u << 20));    // 256 KB (256,512) bf16

  k_prep<<<dim3(640),      256, 0, stream>>>(qkv_w, qkv_s, pw, ps, wqb, pwb);
  k_qkv <<<dim3(6, 4, 32), 256, 0, stream>>>(x, (const u16*)wqb, qkv_b, qfb, kb, vb);
  k_dw  <<<dim3(32*128),   512, 0, stream>>>(qfb, dw_w, dw_s, dw_b, qb);
  k_bias<<<dim3(1024),     256, 0, stream>>>(ab, bidx, biasb);
  k_attn<<<dim3(8, 8, 32), 256, 0, stream>>>(qb, kb, vb, (const u16*)biasb, attn);
  k_proj<<<dim3(2, 4, 32), 256, 0, stream>>>((const u16*)attn, (const u16*)pwb, pb, (float*)d_out);
}

// Round 7
// 258.934 us; speedup vs baseline: 1.2280x; 1.2280x over previous
//
#include <hip/hip_runtime.h>

typedef unsigned int u32;
typedef unsigned short u16;
typedef __attribute__((ext_vector_type(8))) short bf16x8;
typedef __attribute__((ext_vector_type(4))) float f32x4;

constexpr int BATCH = 32;
constexpr int DIM   = 256;
constexpr int NPTS  = 512;
constexpr int NH    = 8;
constexpr int KD    = 16;
constexpr int DHEAD = 64;
constexpr int NH_KD = 128;
constexpr int DH    = 512;

__device__ __forceinline__ float bflo(u32 u){ return __uint_as_float(u << 16); }
__device__ __forceinline__ float bfhi(u32 u){ return __uint_as_float(u & 0xffff0000u); }
__device__ __forceinline__ float bf2f(u16 u){ return __uint_as_float(((u32)u) << 16); }
__device__ __forceinline__ u32 f2bf_bits(float f){
  u32 u = __float_as_uint(f);
  return (u + 0x7fffu + ((u >> 16) & 1u)) >> 16;
}
__device__ __forceinline__ u32 pack2bf(float a, float b){
  return f2bf_bits(a) | (f2bf_bits(b) << 16);
}

union B8 { bf16x8 v; uint2 u2[2]; uint4 u4; };

// ---------------------------------------------------------------------------
// K0: fold scale into weights, convert to bf16.
// ---------------------------------------------------------------------------
__global__ __launch_bounds__(256) void k_prep(
    const float* __restrict__ wq, const float* __restrict__ sq,
    const float* __restrict__ wp, const float* __restrict__ sp,
    u32* __restrict__ wqb, u32* __restrict__ pwb)
{
  int t = blockIdx.x * 256 + threadIdx.x;
  if (t < 98304){                      // 768*256/2
    int i = 2*t;
    float s = sq[i >> 8];
    wqb[t] = pack2bf(wq[i]*s, wq[i+1]*s);
  } else {
    int j = t - 98304;                 // 256*512/2
    int i = 2*j;
    float s = sp[i >> 9];
    pwb[j] = pack2bf(wp[i]*s, wp[i+1]*s);
  }
}

// ---------------------------------------------------------------------------
// K1: qkv MFMA GEMM. C[o 768][n 512] per batch, K=256.
// v is stored with its m(-spatial) columns permuted within 32-blocks so that
// k_attn's transposed-score registers directly form the PV A-fragment:
//   p = (n&~31) | (n&3) | (((n>>4)&1)<<2) | (((n>>2)&3)<<3)
// ---------------------------------------------------------------------------
__global__ __launch_bounds__(256) void k_qkv(
    const float* __restrict__ x, const u16* __restrict__ wqb,
    const float* __restrict__ bias,
    u16* __restrict__ qfb, u16* __restrict__ kb, u16* __restrict__ vb)
{
  __shared__ __align__(16) u16 Xl[128*36];

  const int Mblk = blockIdx.x, Nblk = blockIdx.y, b = blockIdx.z;
  const int tid = threadIdx.x, wave = tid >> 6, lane = tid & 63;
  const int wm = wave >> 1, wn = wave & 1;
  const int c = lane & 15, q = lane >> 4;
  const int Mbase = Mblk*128 + wm*64;

  f32x4 acc[4][4];
  #pragma unroll
  for (int mt = 0; mt < 4; mt++){
    f32x4 bi;
    #pragma unroll
    for (int r = 0; r < 4; r++) bi[r] = bias[Mbase + mt*16 + q*4 + r];
    #pragma unroll
    for (int nt = 0; nt < 4; nt++) acc[mt][nt] = bi;
  }

  const float* xb = x + (size_t)b*DIM*NPTS + Nblk*128;

  for (int kc8 = 0; kc8 < 8; kc8++){
    const int kc = kc8*32;
    __syncthreads();
    #pragma unroll
    for (int it = 0; it < 4; it++){
      int n2 = 2*((tid & 31) + 32*(it & 1));
      int cc = 2*((tid >> 5) + 8*(it >> 1));
      const float* xr = xb + (size_t)(kc + cc)*NPTS + n2;
      float2 A = *(const float2*)xr;
      float2 Bv = *(const float2*)(xr + NPTS);
      *(u32*)(Xl + (size_t)n2*36 + cc)     = pack2bf(A.x, Bv.x);
      *(u32*)(Xl + (size_t)(n2+1)*36 + cc) = pack2bf(A.y, Bv.y);
    }
    __syncthreads();

    bf16x8 aW[4];
    #pragma unroll
    for (int mt = 0; mt < 4; mt++)
      aW[mt] = *(const bf16x8*)(wqb + (size_t)(Mbase + mt*16 + c)*256 + kc + q*8);
    B8 bX[4];
    #pragma unroll
    for (int nt = 0; nt < 4; nt++){
      const u16* base = Xl + (size_t)(wn*64 + nt*16 + c)*36 + q*8;
      bX[nt].u2[0] = *(const uint2*)(base);
      bX[nt].u2[1] = *(const uint2*)(base + 4);
    }
    #pragma unroll
    for (int mt = 0; mt < 4; mt++)
      #pragma unroll
      for (int nt = 0; nt < 4; nt++)
        acc[mt][nt] = __builtin_amdgcn_mfma_f32_16x16x32_bf16(
            aW[mt], bX[nt].v, acc[mt][nt], 0, 0, 0);
  }

  #pragma unroll
  for (int mt = 0; mt < 4; mt++){
    const int ob = wm*64 + mt*16 + q*4;
    #pragma unroll
    for (int nt = 0; nt < 4; nt++){
      const int n = Nblk*128 + wn*64 + nt*16 + c;
      #pragma unroll
      for (int r = 0; r < 4; r++){
        u16 bv = (u16)f2bf_bits(acc[mt][nt][r]);
        int ol = ob + r;
        if (Mblk == 0){
          qfb[((size_t)b*NH_KD + ol)*NPTS + n] = bv;
        } else if (Mblk == 1){
          kb[(((size_t)b*NH + (ol >> 4))*NPTS + n)*16 + (ol & 15)] = bv;
        } else {
          int d = (Mblk - 2)*128 + ol;
          int p = (n & ~31) | (n & 3) | (((n >> 4) & 1) << 2) | (((n >> 2) & 3) << 3);
          vb[((size_t)b*DH + d)*NPTS + p] = bv;
        }
      }
    }
  }
}

// ---------------------------------------------------------------------------
// K2: depthwise 3x3x3 conv + scale/bias, x0.25 folded, bf16 in/out.
// ---------------------------------------------------------------------------
__global__ __launch_bounds__(512) void k_dw(
    const u16* __restrict__ qfb, const float* __restrict__ dww,
    const float* __restrict__ dws, const float* __restrict__ dwb,
    u16* __restrict__ qb)
{
  const int bc = blockIdx.x;            // b*128 + ch
  const int b  = bc >> 7;
  const int ch = bc & 127;
  const int n  = threadIdx.x;
  const int z = n >> 6, y = (n >> 3) & 7, xx = n & 7;
  float wv[27];
  #pragma unroll
  for (int i = 0; i < 27; i++) wv[i] = dww[ch*27 + i];
  const u16* qp = qfb + (size_t)bc * NPTS;
  float acc = 0.f;
  #pragma unroll
  for (int dz = 0; dz < 3; dz++){
    int zz = z + dz - 1; if ((unsigned)zz > 7u) continue;
    #pragma unroll
    for (int dy = 0; dy < 3; dy++){
      int yy = y + dy - 1; if ((unsigned)yy > 7u) continue;
      #pragma unroll
      for (int dx = 0; dx < 3; dx++){
        int xw = xx + dx - 1; if ((unsigned)xw > 7u) continue;
        acc += bf2f(qp[zz*64 + yy*8 + xw]) * wv[dz*9 + dy*3 + dx];
      }
    }
  }
  acc = (acc * dws[ch] + dwb[ch]) * 0.25f;   // fold 1/sqrt(KD)
  int hh = ch >> 4, cc = ch & 15;
  qb[(((size_t)b*NH + hh)*NPTS + n)*16 + cc] = (u16)f2bf_bits(acc);
}

// ---------------------------------------------------------------------------
// K_bias: bf16 bias table in TRANSPOSED-score C-layout:
// biasb[h][mtg 32][ntile 32][lane 64][r 4] u16, value = bias(m,n) with
// m = mtg*16 + (lane>>4)*4 + r, n = ntile*16 + (lane&15).
// ---------------------------------------------------------------------------
__global__ __launch_bounds__(256) void k_bias(
    const float* __restrict__ ab, const int* __restrict__ bidx,
    u32* __restrict__ biasb)
{
  const int blk = blockIdx.x;
  const int mtg = blk >> 5, ntile = blk & 31;
  const int lane = threadIdx.x & 63;
  const int h0 = threadIdx.x >> 6;
  const int qq = lane >> 4;
  const int n = ntile*16 + (lane & 15);
  int idx[4];
  #pragma unroll
  for (int r = 0; r < 4; r++)
    idx[r] = bidx[(size_t)n*NPTS + mtg*16 + qq*4 + r];
  for (int h = h0; h < NH; h += 4){
    float v0 = ab[h*NPTS + idx[0]], v1 = ab[h*NPTS + idx[1]];
    float v2 = ab[h*NPTS + idx[2]], v3 = ab[h*NPTS + idx[3]];
    u32* dst = biasb + (((size_t)(h*32 + mtg)*32 + ntile)*64 + lane)*2;
    dst[0] = pack2bf(v0, v1);
    dst[1] = pack2bf(v2, v3);
  }
}

// ---------------------------------------------------------------------------
// K3: LDS-free barrier-free MFMA flash attention, transposed scores.
// Grid (b*8+h, tg): tg-siblings stride 256 -> same XCD; h pins bias slice.
// Per wave: 16 n-rows. S^T = mfma(A=K, B=Q, C=bias^T): lane holds n=c,
// m=q*4+r. exp() streamed; two adjacent tiles' packed exps ARE the PV
// A-frag because V's m-columns were permuted at write time. O in C-layout
// (n=q*4+r, d=c+16*dt); l = per-lane scalar + 2 shuffles.
// ---------------------------------------------------------------------------
__global__ __launch_bounds__(256, 4) void k_attn(
    const u16* __restrict__ qb, const u16* __restrict__ kb,
    const u16* __restrict__ vb, const u16* __restrict__ biasb,
    u16* __restrict__ attnout)
{
  const int hb = blockIdx.x, tg = blockIdx.y;
  const int b = hb >> 3, h = hb & 7;
  const int lane = threadIdx.x & 63, wave = threadIdx.x >> 6;
  const int c = lane & 15, q = lane >> 4;
  const int bh = b*NH + h;
  const int ntile = tg*4 + wave;        // 0..31
  const int n0w = ntile*16;

  const bf16x8 zfrag = {0,0,0,0,0,0,0,0};
  bf16x8 bQ = zfrag;
  if (q < 2)
    bQ = *(const bf16x8*)(qb + (((size_t)bh*NPTS + n0w + c) << 4) + q*8);

  const u16* kbh   = kb + ((size_t)bh*NPTS)*16;
  const u16* vbh   = vb + ((size_t)b*DH + h*DHEAD)*NPTS;
  const u16* biasw = biasb + (size_t)h*262144 + (size_t)ntile*256 + lane*4;

  f32x4 O[4] = {{0,0,0,0},{0,0,0,0},{0,0,0,0},{0,0,0,0}};
  float lsum = 0.f;

  for (int win = 0; win < 16; win++){     // 32 m per window
    u32 pp[4];
    #pragma unroll
    for (int t = 0; t < 2; t++){
      const int mtg = win*2 + t;
      bf16x8 aK = zfrag;
      if (q < 2)
        aK = *(const bf16x8*)(kbh + (((size_t)(mtg*16 + c)) << 4) + q*8);
      uint2 bu = *(const uint2*)(biasw + (size_t)mtg*8192);
      f32x4 bias4;
      bias4[0] = bflo(bu.x); bias4[1] = bfhi(bu.x);
      bias4[2] = bflo(bu.y); bias4[3] = bfhi(bu.y);
      f32x4 S = __builtin_amdgcn_mfma_f32_16x16x32_bf16(aK, bQ, bias4, 0, 0, 0);
      float e0 = __expf(S[0]), e1 = __expf(S[1]);
      float e2 = __expf(S[2]), e3 = __expf(S[3]);
      lsum += (e0 + e1) + (e2 + e3);
      pp[t*2 + 0] = pack2bf(e0, e1);
      pp[t*2 + 1] = pack2bf(e2, e3);
    }
    B8 aP; aP.u4 = make_uint4(pp[0], pp[1], pp[2], pp[3]);
    const int mv = win*32 + q*8;
    #pragma unroll
    for (int dt = 0; dt < 4; dt++){
      bf16x8 bV = *(const bf16x8*)(vbh + (size_t)(dt*16 + c)*NPTS + mv);
      O[dt] = __builtin_amdgcn_mfma_f32_16x16x32_bf16(aP.v, bV, O[dt], 0, 0, 0);
    }
  }

  // l: reduce over the 4 m-quads (lanes differing in bits 4-5)
  lsum += __shfl_xor(lsum, 16, 64);
  lsum += __shfl_xor(lsum, 32, 64);
  f32x4 inv;
  #pragma unroll
  for (int r = 0; r < 4; r++)
    inv[r] = 1.0f / __shfl(lsum, q*4 + r, 64);   // lane (q*4+r) has l for n=q*4+r

  // epilogue: relu(O/l) -> attn[b][n][dh] bf16, scalar u16 stores
  u16* ao = attnout + ((size_t)(b*NPTS + n0w))*DH + h*DHEAD;
  #pragma unroll
  for (int dt = 0; dt < 4; dt++)
    #pragma unroll
    for (int r = 0; r < 4; r++)
      ao[(size_t)(q*4 + r)*DH + dt*16 + c] =
          (u16)f2bf_bits(fmaxf(O[dt][r]*inv[r], 0.f));
}

// ---------------------------------------------------------------------------
// K4: proj MFMA GEMM (unchanged).
// ---------------------------------------------------------------------------
__global__ __launch_bounds__(256) void k_proj(
    const u16* __restrict__ attn, const u16* __restrict__ pwb,
    const float* __restrict__ bias, float* __restrict__ out)
{
  const int Mblk = blockIdx.x, Nblk = blockIdx.y, b = blockIdx.z;
  const int tid = threadIdx.x, wave = tid >> 6, lane = tid & 63;
  const int wm = wave >> 1, wn = wave & 1;
  const int c = lane & 15, q = lane >> 4;
  const int Mbase = Mblk*128 + wm*64;
  const int Nbase = Nblk*128 + wn*64;

  f32x4 acc[4][4];
  #pragma unroll
  for (int mt = 0; mt < 4; mt++){
    f32x4 bi;
    #pragma unroll
    for (int r = 0; r < 4; r++) bi[r] = bias[Mbase + mt*16 + q*4 + r];
    #pragma unroll
    for (int nt = 0; nt < 4; nt++) acc[mt][nt] = bi;
  }

  const u16* arow = attn + (size_t)b*NPTS*DH;

  for (int kc8 = 0; kc8 < 16; kc8++){
    const int kc = kc8*32;
    bf16x8 aW[4], bA[4];
    #pragma unroll
    for (int mt = 0; mt < 4; mt++)
      aW[mt] = *(const bf16x8*)(pwb + (size_t)(Mbase + mt*16 + c)*DH + kc + q*8);
    #pragma unroll
    for (int nt = 0; nt < 4; nt++)
      bA[nt] = *(const bf16x8*)(arow + (size_t)(Nbase + nt*16 + c)*DH + kc + q*8);
    #pragma unroll
    for (int mt = 0; mt < 4; mt++)
      #pragma unroll
      for (int nt = 0; nt < 4; nt++)
        acc[mt][nt] = __builtin_amdgcn_mfma_f32_16x16x32_bf16(
            aW[mt], bA[nt], acc[mt][nt], 0, 0, 0);
  }

  #pragma unroll
  for (int mt = 0; mt < 4; mt++){
    #pragma unroll
    for (int nt = 0; nt < 4; nt++){
      const int n = Nbase + nt*16 + c;
      #pragma unroll
      for (int r = 0; r < 4; r++){
        int o = Mbase + mt*16 + q*4 + r;
        out[((size_t)b*DIM + o)*NPTS + n] = acc[mt][nt][r];
      }
    }
  }
}

// ---------------------------------------------------------------------------
extern "C" void kernel_launch(void* const* d_in, const int* in_sizes, int n_in,
                              void* d_out, int out_size, void* d_ws, size_t ws_size,
                              hipStream_t stream)
{
  const float* x     = (const float*)d_in[0];
  const float* qkv_w = (const float*)d_in[1];
  const float* qkv_s = (const float*)d_in[2];
  const float* qkv_b = (const float*)d_in[3];
  const float* dw_w  = (const float*)d_in[4];
  const float* dw_s  = (const float*)d_in[5];
  const float* dw_b  = (const float*)d_in[6];
  const float* ab    = (const float*)d_in[7];
  const float* pw    = (const float*)d_in[8];
  const float* ps    = (const float*)d_in[9];
  const float* pb    = (const float*)d_in[10];
  const int* bidx    = (const int*)d_in[11];

  char* ws = (char*)d_ws;
  u16*   qfb   = (u16*)  (ws);                  //  4 MB (B,128,512) bf16
  u16*   qb    = (u16*)  (ws + ( 4u << 20));    //  4 MB (B,8,512,16) bf16
  u16*   kb    = (u16*)  (ws + ( 8u << 20));    //  4 MB (B,8,512,16) bf16
  u16*   vb    = (u16*)  (ws + (12u << 20));    // 16 MB (B,512,512) bf16 [b][d][p]
  u16*   attn  = (u16*)  (ws + (28u << 20));    // 16 MB (B,512,512) bf16 rows [n][dh]
  u32*   biasb = (u32*)  (ws + (44u << 20));    //  4 MB (8,32,32,64,4) bf16 S^T layout
  u32*   wqb   = (u32*)  (ws + (48u << 20));    // 384 KB (768,256) bf16
  u32*   pwb   = (u32*)  (ws + (49u << 20));    // 256 KB (256,512) bf16

  k_prep<<<dim3(640),      256, 0, stream>>>(qkv_w, qkv_s, pw, ps, wqb, pwb);
  k_qkv <<<dim3(6, 4, 32), 256, 0, stream>>>(x, (const u16*)wqb, qkv_b, qfb, kb, vb);
  k_dw  <<<dim3(32*128),   512, 0, stream>>>(qfb, dw_w, dw_s, dw_b, qb);
  k_bias<<<dim3(1024),     256, 0, stream>>>(ab, bidx, biasb);
  k_attn<<<dim3(256, 8),   256, 0, stream>>>(qb, kb, vb, (const u16*)biasb, attn);
  k_proj<<<dim3(2, 4, 32), 256, 0, stream>>>(attn, (const u16*)pwb, pb, (float*)d_out);
}